// Round 4
// baseline (19663.155 us; speedup 1.0000x reference)
//
#include <hip/hip_runtime.h>
#include <math.h>

#define TT 32
#define DD 64
#define NN 1024
#define VV 64
#define RR 4
#define HH 512
#define DINN 320   // D + R*V
#define NTHREADS 1024

typedef unsigned int uint_t;
typedef unsigned short ushort_t;

__device__ __forceinline__ float sigf(float x) { return 1.0f / (1.0f + __expf(-x)); }
__device__ __forceinline__ float splus(float x) {
  return (x > 0.f) ? (x + log1pf(__expf(-x))) : log1pf(__expf(x));
}
__device__ __forceinline__ float dot4f(float4 a, float4 b) {
  return a.x * b.x + a.y * b.y + a.z * b.z + a.w * b.w;
}
// 8 bf16 weights (as uint4) dotted with 8 fp32 activations
__device__ __forceinline__ float dot8bf(uint4 w, float4 ha, float4 hb) {
  float s;
  s  = __uint_as_float(w.x << 16) * ha.x + __uint_as_float(w.x & 0xffff0000u) * ha.y;
  s += __uint_as_float(w.y << 16) * ha.z + __uint_as_float(w.y & 0xffff0000u) * ha.w;
  s += __uint_as_float(w.z << 16) * hb.x + __uint_as_float(w.z & 0xffff0000u) * hb.y;
  s += __uint_as_float(w.w << 16) * hb.z + __uint_as_float(w.w & 0xffff0000u) * hb.w;
  return s;
}
__device__ __forceinline__ ushort_t bfr(float f) {
  uint_t u = __float_as_uint(f);
  return (ushort_t)((u + 0x7fffu + ((u >> 16) & 1u)) >> 16);
}
__device__ __forceinline__ float bflo(uint_t u) { return __uint_as_float(u << 16); }
__device__ __forceinline__ float bfhi(uint_t u) { return __uint_as_float(u & 0xffff0000u); }

// addressing over bf16 mem rows. All 1024 threads. 3 internal syncs.
__device__ __forceinline__ void addressing(
    const float* __restrict__ oarr, int slot, const ushort_t* __restrict__ membf,
    float* __restrict__ s_ws, float* __restrict__ s_scr,
    const float* __restrict__ s_norm2, float* __restrict__ s_red,
    const float* easrc, float* __restrict__ s_e, float* __restrict__ s_a,
    int tid, int lane, int wave) {
  const uint4* row = (const uint4*)(membf + (size_t)tid * VV);
  uint4 rb[8];
  #pragma unroll
  for (int p = 0; p < 8; ++p) rb[p] = row[p];   // full row in flight
  const float4* o4 = (const float4*)oarr;
  float dotv = 0.f, kk = 0.f;
  #pragma unroll
  for (int p = 0; p < 8; ++p) {
    float4 oa = o4[2 * p], ob = o4[2 * p + 1];
    float k0 = oa.x + 1e-16f, k1 = oa.y + 1e-16f, k2 = oa.z + 1e-16f, k3 = oa.w + 1e-16f;
    float k4 = ob.x + 1e-16f, k5 = ob.y + 1e-16f, k6 = ob.z + 1e-16f, k7 = ob.w + 1e-16f;
    kk += k0 * k0 + k1 * k1 + k2 * k2 + k3 * k3 + k4 * k4 + k5 * k5 + k6 * k6 + k7 * k7;
    dotv += (bflo(rb[p].x) + 1e-16f) * k0 + (bfhi(rb[p].x) + 1e-16f) * k1 +
            (bflo(rb[p].y) + 1e-16f) * k2 + (bfhi(rb[p].y) + 1e-16f) * k3 +
            (bflo(rb[p].z) + 1e-16f) * k4 + (bfhi(rb[p].z) + 1e-16f) * k5 +
            (bflo(rb[p].w) + 1e-16f) * k6 + (bfhi(rb[p].w) + 1e-16f) * k7;
  }
  // redundant per-thread scalars (cheap; saves a phase+sync)
  float nb = fmaxf(sqrtf(kk), 1e-8f);
  float beta = splus(oarr[64]);
  float g = sigf(oarr[65]);
  float a0 = oarr[66], a1 = oarr[67], a2 = oarr[68];
  float mx = fmaxf(a0, fmaxf(a1, a2));
  float e0 = __expf(a0 - mx), e1 = __expf(a1 - mx), e2 = __expf(a2 - mx);
  float sinv = 1.0f / (e0 + e1 + e2);
  float s0 = e0 * sinv, s1 = e1 * sinv, s2 = e2 * sinv;
  float gamma = 1.0f + splus(oarr[69]);
  float na = fmaxf(sqrtf(s_norm2[tid]), 1e-8f);
  float z = beta * dotv / (na * nb);
  float ee = __expf(z);                    // no max-sub: |z| <= beta (small)
  float v = ee;
  #pragma unroll
  for (int o = 32; o; o >>= 1) v += __shfl_xor(v, o);
  if (lane == 0) s_red[wave] = v;
  __syncthreads();                         // (A)
  if (easrc && tid >= 960) {               // idle-ish lanes prep erase/add vecs
    int q = tid - 960;
    s_e[q] = sigf(easrc[q]);
    s_a[q] = easrc[64 + q];
  }
  float S = 0.f;
  #pragma unroll
  for (int w = 0; w < 16; ++w) S += s_red[w];
  float wc = ee / S;
  float wgv = g * wc + (1.0f - g) * s_ws[slot * NN + tid];
  s_scr[1024 + tid] = wgv;
  __syncthreads();                         // (B)
  const float* wg = s_scr + 1024;
  float wsn = s0 * wg[(tid + 1023) & 1023] + s1 * wg[tid] + s2 * wg[(tid + 1) & 1023];
  float wp = __expf(gamma * __logf(wsn));
  v = wp;
  #pragma unroll
  for (int o = 32; o; o >>= 1) v += __shfl_xor(v, o);
  if (lane == 0) s_red[wave] = v;
  __syncthreads();                         // (C)
  float Z = 0.f;
  #pragma unroll
  for (int w = 0; w < 16; ++w) Z += s_red[w];
  float wfin = wp / (Z + 1e-16f);
  s_scr[tid] = wfin;                       // same-thread readable immediately
  s_ws[slot * NN + tid] = wfin;
}

__global__ __launch_bounds__(NTHREADS, 1) void ntm_fwd(
    const float* __restrict__ x, const float* __restrict__ mem_bias,
    const float* __restrict__ h_bias, const float* __restrict__ c_bias,
    const float* __restrict__ gbias,
    const ushort_t* __restrict__ bWih, const ushort_t* __restrict__ bWhh,
    const ushort_t* __restrict__ brW, const ushort_t* __restrict__ bwW,
    const float* __restrict__ read_b, const float* __restrict__ write_b,
    const float* __restrict__ read_init,
    const ushort_t* __restrict__ bOutW, const float* __restrict__ out_b,
    float* __restrict__ out, ushort_t* __restrict__ wsmem) {
  const int b = blockIdx.x;
  const int tid = threadIdx.x;
  const int lane = tid & 63;
  const int wave = tid >> 6;

  __shared__ float s_ws[8 * NN];                 // shift-weight history (32 KB)
  __shared__ alignas(16) float s_scr[2048];      // gates | w[0:1024], wg[1024:2048]
  __shared__ alignas(16) float s_h[HH];
  __shared__ float s_c[HH];
  __shared__ alignas(16) float s_fx[768];        // cx (320) | final_x (768)
  __shared__ float s_norm2[NN];
  __shared__ float s_redbuf[16 * 64];
  __shared__ alignas(16) float s_reads[RR * VV];
  __shared__ alignas(16) float s_or[72];
  __shared__ alignas(16) float s_ow[200];
  __shared__ alignas(16) float s_e[VV];
  __shared__ alignas(16) float s_a[VV];
  __shared__ float s_red[16];

  ushort_t* membf = wsmem + (size_t)b * (NN * VV);

  { // init: convert this block's mem to bf16 + state
    for (int i = tid; i < HH; i += NTHREADS) { s_h[i] = h_bias[i]; s_c[i] = c_bias[i]; }
    for (int i = tid; i < RR * VV; i += NTHREADS) s_reads[i] = read_init[i];
    for (int i = tid; i < 8 * NN; i += NTHREADS) s_ws[i] = 0.0f;
    // row `tid` of mem_bias -> bf16, norm from rounded values
    const float4* src = (const float4*)(mem_bias + (size_t)tid * VV);
    uint4* dst = (uint4*)(membf + (size_t)tid * VV);
    float nacc = 0.f;
    #pragma unroll
    for (int p = 0; p < 8; ++p) {
      float4 va = src[2 * p], vb = src[2 * p + 1];
      uint_t u0 = bfr(va.x), u1 = bfr(va.y), u2 = bfr(va.z), u3 = bfr(va.w);
      uint_t u4 = bfr(vb.x), u5 = bfr(vb.y), u6 = bfr(vb.z), u7 = bfr(vb.w);
      uint4 o;
      o.x = u0 | (u1 << 16); o.y = u2 | (u3 << 16);
      o.z = u4 | (u5 << 16); o.w = u6 | (u7 << 16);
      dst[p] = o;
      float r0 = bflo(o.x) + 1e-16f, r1 = bfhi(o.x) + 1e-16f;
      float r2 = bflo(o.y) + 1e-16f, r3 = bfhi(o.y) + 1e-16f;
      float r4 = bflo(o.z) + 1e-16f, r5 = bfhi(o.z) + 1e-16f;
      float r6 = bflo(o.w) + 1e-16f, r7 = bfhi(o.w) + 1e-16f;
      nacc += r0 * r0 + r1 * r1 + r2 * r2 + r3 * r3 + r4 * r4 + r5 * r5 + r6 * r6 + r7 * r7;
    }
    s_norm2[tid] = nacc;
  }
  __syncthreads();

  for (int t = 0; t < TT; ++t) {
    // phase0: contr_x = [x_t, reads]
    if (tid < DD) s_fx[tid] = x[((size_t)b * TT + t) * DD + tid];
    else if (tid < DINN) s_fx[tid] = s_reads[tid - DD];
    __syncthreads();

    // phase1: gates GEMV, bf16 weights, 2 rows/thread, 16 loads in flight/chunk
    {
      const uint4* wi0 = (const uint4*)(bWih + (size_t)tid * DINN);
      const uint4* wi1 = (const uint4*)(bWih + (size_t)(tid + 1024) * DINN);
      const uint4* wh0 = (const uint4*)(bWhh + (size_t)tid * HH);
      const uint4* wh1 = (const uint4*)(bWhh + (size_t)(tid + 1024) * HH);
      const float4* cx = (const float4*)s_fx;
      const float4* h4 = (const float4*)s_h;
      float acc0 = gbias[tid], acc1 = gbias[tid + 1024];
      #pragma unroll
      for (int c = 0; c < 5; ++c) {              // Wih: 40 uint4/row
        uint4 a0[8], a1[8];
        #pragma unroll
        for (int q = 0; q < 8; ++q) { a0[q] = wi0[c * 8 + q]; a1[q] = wi1[c * 8 + q]; }
        #pragma unroll
        for (int q = 0; q < 8; ++q) {
          float4 ha = cx[(c * 8 + q) * 2], hb = cx[(c * 8 + q) * 2 + 1];
          acc0 += dot8bf(a0[q], ha, hb);
          acc1 += dot8bf(a1[q], ha, hb);
        }
      }
      #pragma unroll
      for (int c = 0; c < 8; ++c) {              // Whh: 64 uint4/row
        uint4 a0[8], a1[8];
        #pragma unroll
        for (int q = 0; q < 8; ++q) { a0[q] = wh0[c * 8 + q]; a1[q] = wh1[c * 8 + q]; }
        #pragma unroll
        for (int q = 0; q < 8; ++q) {
          float4 ha = h4[(c * 8 + q) * 2], hb = h4[(c * 8 + q) * 2 + 1];
          acc0 += dot8bf(a0[q], ha, hb);
          acc1 += dot8bf(a1[q], ha, hb);
        }
      }
      s_scr[tid] = acc0;
      s_scr[tid + 1024] = acc1;
    }
    __syncthreads();

    // phase2: LSTM elementwise
    if (tid < HH) {
      float gi = s_scr[tid], gf = s_scr[HH + tid];
      float gg = s_scr[2 * HH + tid], go = s_scr[3 * HH + tid];
      float cn = sigf(gf) * s_c[tid] + sigf(gi) * tanhf(gg);
      float hn = sigf(go) * tanhf(cn);
      s_c[tid] = cn;
      s_h[tid] = hn;
    }
    __syncthreads();

    for (int hd = 0; hd < RR; ++hd) {
      // read GEMV: 70 outputs x 8 sublanes, interleaved, loads upfront
      if (tid < 560) {
        int j = tid >> 3, sub = tid & 7;
        const uint4* wr = (const uint4*)(brW + (((size_t)hd * 70 + j) << 9));
        const float4* h4 = (const float4*)s_h;
        uint4 wbuf[8];
        #pragma unroll
        for (int p = 0; p < 8; ++p) wbuf[p] = wr[p * 8 + sub];
        float acc = 0.f;
        #pragma unroll
        for (int p = 0; p < 8; ++p) {
          int o = p * 16 + sub * 2;
          acc += dot8bf(wbuf[p], h4[o], h4[o + 1]);
        }
        acc += __shfl_xor(acc, 1); acc += __shfl_xor(acc, 2); acc += __shfl_xor(acc, 4);
        if (sub == 0) s_or[j] = acc + read_b[hd * 70 + j];
      }
      __syncthreads();

      addressing(s_or, 2 * hd, membf, s_ws, s_scr, s_norm2,
                 s_red, nullptr, s_e, s_a, tid, lane, wave);
      __syncthreads();   // w visible cross-thread for einsum

      { // read einsum partials: wave handles 64 rows, lane = column (coalesced)
        float acc = 0.f;
        int base = wave * 64;
        #pragma unroll 8
        for (int r = 0; r < 64; ++r)
          acc += s_scr[base + r] * bflo((uint_t)membf[(size_t)(base + r) * VV + lane]);
        s_redbuf[wave * 64 + lane] = acc;
      }
      __syncthreads();

      // write GEMV (198 x 4 sublanes) + read-combine on idle wave 15
      if (tid < 792) {
        int j = tid >> 2, sub = tid & 3;
        const uint4* ww = (const uint4*)(bwW + (((size_t)hd * 198 + j) << 9));
        const float4* h4 = (const float4*)s_h;
        float acc = 0.f;
        #pragma unroll
        for (int c = 0; c < 2; ++c) {
          uint4 wbuf[8];
          #pragma unroll
          for (int p = 0; p < 8; ++p) wbuf[p] = ww[(c * 8 + p) * 4 + sub];
          #pragma unroll
          for (int p = 0; p < 8; ++p) {
            int o = (c * 8 + p) * 8 + sub * 2;
            acc += dot8bf(wbuf[p], h4[o], h4[o + 1]);
          }
        }
        acc += __shfl_xor(acc, 1); acc += __shfl_xor(acc, 2);
        if (sub == 0) s_ow[j] = acc + write_b[hd * 198 + j];
      }
      if (tid >= 960) {
        int q = tid - 960;
        float s = 0.f;
        #pragma unroll
        for (int w = 0; w < 16; ++w) s += s_redbuf[w * 64 + q];
        s_reads[hd * VV + q] = s;
      }
      __syncthreads();

      addressing(s_ow, 2 * hd + 1, membf, s_ws, s_scr, s_norm2,
                 s_red, s_ow + 70, s_e, s_a, tid, lane, wave);

      { // erase/add (bf16 RMW) + norm recompute from rounded values
        float w2n = s_scr[tid];
        uint4* rowm = (uint4*)(membf + (size_t)tid * VV);
        uint4 rb[8];
        #pragma unroll
        for (int p = 0; p < 8; ++p) rb[p] = rowm[p];
        const float4* e4 = (const float4*)s_e;
        const float4* a4 = (const float4*)s_a;
        float nacc = 0.f;
        #pragma unroll
        for (int p = 0; p < 8; ++p) {
          float4 ev = e4[2 * p], ev2 = e4[2 * p + 1];
          float4 av = a4[2 * p], av2 = a4[2 * p + 1];
          float m0 = bflo(rb[p].x) * (1.0f - w2n * ev.x) + w2n * av.x;
          float m1 = bfhi(rb[p].x) * (1.0f - w2n * ev.y) + w2n * av.y;
          float m2 = bflo(rb[p].y) * (1.0f - w2n * ev.z) + w2n * av.z;
          float m3 = bfhi(rb[p].y) * (1.0f - w2n * ev.w) + w2n * av.w;
          float m4 = bflo(rb[p].z) * (1.0f - w2n * ev2.x) + w2n * av2.x;
          float m5 = bfhi(rb[p].z) * (1.0f - w2n * ev2.y) + w2n * av2.y;
          float m6 = bflo(rb[p].w) * (1.0f - w2n * ev2.z) + w2n * av2.z;
          float m7 = bfhi(rb[p].w) * (1.0f - w2n * ev2.w) + w2n * av2.w;
          uint_t u0 = bfr(m0), u1 = bfr(m1), u2 = bfr(m2), u3 = bfr(m3);
          uint_t u4 = bfr(m4), u5 = bfr(m5), u6 = bfr(m6), u7 = bfr(m7);
          uint4 o;
          o.x = u0 | (u1 << 16); o.y = u2 | (u3 << 16);
          o.z = u4 | (u5 << 16); o.w = u6 | (u7 << 16);
          rowm[p] = o;
          float r0 = bflo(o.x) + 1e-16f, r1 = bfhi(o.x) + 1e-16f;
          float r2 = bflo(o.y) + 1e-16f, r3 = bfhi(o.y) + 1e-16f;
          float r4 = bflo(o.z) + 1e-16f, r5 = bfhi(o.z) + 1e-16f;
          float r6 = bflo(o.w) + 1e-16f, r7 = bfhi(o.w) + 1e-16f;
          nacc += r0 * r0 + r1 * r1 + r2 * r2 + r3 * r3 +
                  r4 * r4 + r5 * r5 + r6 * r6 + r7 * r7;
        }
        s_norm2[tid] = nacc;
      }
      // no sync: next phase touches disjoint data; mem/norm re-read same-thread first
    } // heads

    // final_x = [co, reads]
    if (tid < 768) s_fx[tid] = (tid < HH) ? s_h[tid] : s_reads[tid - HH];
    __syncthreads();

    // out GEMV (bf16 weights; interleaved sublanes; 12 loads upfront)
    if (tid < 512) {
      int j = tid >> 3, sub = tid & 7;
      const uint4* wo = (const uint4*)(bOutW + (size_t)j * 768);
      const float4* f4 = (const float4*)s_fx;
      uint4 wbuf[12];
      #pragma unroll
      for (int p = 0; p < 12; ++p) wbuf[p] = wo[p * 8 + sub];
      float acc = 0.f;
      #pragma unroll
      for (int p = 0; p < 12; ++p) {
        int o = (p * 8 + sub) * 2;
        acc += dot8bf(wbuf[p], f4[o], f4[o + 1]);
      }
      acc += __shfl_xor(acc, 1); acc += __shfl_xor(acc, 2); acc += __shfl_xor(acc, 4);
      if (sub == 0) out[((size_t)b * TT + t) * DD + j] = sigf(acc + out_b[j]);
    }
    __syncthreads();
  } // t
}

// ---- weight pre-conversion (runs every launch; deterministic) ----
__global__ void f2bf_kernel(const float4* __restrict__ src, ushort4* __restrict__ dst, int n4) {
  int i = blockIdx.x * 256 + threadIdx.x;
  if (i < n4) {
    float4 v = src[i];
    ushort4 o;
    o.x = bfr(v.x); o.y = bfr(v.y); o.z = bfr(v.z); o.w = bfr(v.w);
    dst[i] = o;
  }
}
__global__ void bias_kernel(const float* __restrict__ bi, const float* __restrict__ bh,
                            float* __restrict__ o) {
  int i = blockIdx.x * 256 + threadIdx.x;
  if (i < 2048) o[i] = bi[i] + bh[i];
}

extern "C" void kernel_launch(void* const* d_in, const int* in_sizes, int n_in,
                              void* d_out, int out_size, void* d_ws, size_t ws_size,
                              hipStream_t stream) {
  char* ws = (char*)d_ws;
  ushort_t* membf = (ushort_t*)ws;                 // 64*1024*64*2 = 8,388,608 B
  ushort_t* bWih = (ushort_t*)(ws + 8388608);      // 2048*320*2  = 1,310,720
  ushort_t* bWhh = (ushort_t*)(ws + 9699328);      // 2048*512*2  = 2,097,152
  ushort_t* brW  = (ushort_t*)(ws + 11796480);     // 4*70*512*2  =   286,720
  ushort_t* bwW  = (ushort_t*)(ws + 12083200);     // 4*198*512*2 =   811,008
  ushort_t* bOutW= (ushort_t*)(ws + 12894208);     // 64*768*2    =    98,304
  float* gbias   = (float*)(ws + 12992512);        // 2048*4      =     8,192

  const int nWih = 2048 * DINN, nWhh = 2048 * HH, nrW = RR * 70 * HH,
            nwW = RR * 198 * HH, nOut = DD * 768;
  f2bf_kernel<<<(nWih / 4 + 255) / 256, 256, 0, stream>>>((const float4*)d_in[4], (ushort4*)bWih, nWih / 4);
  f2bf_kernel<<<(nWhh / 4 + 255) / 256, 256, 0, stream>>>((const float4*)d_in[5], (ushort4*)bWhh, nWhh / 4);
  f2bf_kernel<<<(nrW / 4 + 255) / 256, 256, 0, stream>>>((const float4*)d_in[8], (ushort4*)brW, nrW / 4);
  f2bf_kernel<<<(nwW / 4 + 255) / 256, 256, 0, stream>>>((const float4*)d_in[10], (ushort4*)bwW, nwW / 4);
  f2bf_kernel<<<(nOut / 4 + 255) / 256, 256, 0, stream>>>((const float4*)d_in[13], (ushort4*)bOutW, nOut / 4);
  bias_kernel<<<8, 256, 0, stream>>>((const float*)d_in[6], (const float*)d_in[7], gbias);

  ntm_fwd<<<dim3(64), dim3(NTHREADS), 0, stream>>>(
      (const float*)d_in[0], (const float*)d_in[1], (const float*)d_in[2],
      (const float*)d_in[3], gbias, bWih, bWhh, brW, bwW,
      (const float*)d_in[9], (const float*)d_in[11], (const float*)d_in[12],
      bOutW, (const float*)d_in[14],
      (float*)d_out, membf);
}

// Round 5
// 9320.889 us; speedup vs baseline: 2.1096x; 2.1096x over previous
//
#include <hip/hip_runtime.h>
#include <math.h>

#define TT 32
#define DD 64
#define NN 1024
#define VV 64
#define RR 4
#define HH 512
#define DINN 320   // D + R*V
#define NTHREADS 1024

typedef unsigned int uint_t;
typedef unsigned short ushort_t;

__device__ __forceinline__ float sigf(float x) { return 1.0f / (1.0f + __expf(-x)); }
__device__ __forceinline__ float splus(float x) {
  return (x > 0.f) ? (x + log1pf(__expf(-x))) : log1pf(__expf(x));
}
// 8 bf16 weights (as uint4) dotted with 8 fp32 activations
__device__ __forceinline__ float dot8bf(uint4 w, float4 ha, float4 hb) {
  float s;
  s  = __uint_as_float(w.x << 16) * ha.x + __uint_as_float(w.x & 0xffff0000u) * ha.y;
  s += __uint_as_float(w.y << 16) * ha.z + __uint_as_float(w.y & 0xffff0000u) * ha.w;
  s += __uint_as_float(w.z << 16) * hb.x + __uint_as_float(w.z & 0xffff0000u) * hb.y;
  s += __uint_as_float(w.w << 16) * hb.z + __uint_as_float(w.w & 0xffff0000u) * hb.w;
  return s;
}
__device__ __forceinline__ ushort_t bfr(float f) {
  uint_t u = __float_as_uint(f);
  return (ushort_t)((u + 0x7fffu + ((u >> 16) & 1u)) >> 16);
}

// 4-block group barrier. Monotonic-epoch counter (zeroed by zero_cnt each launch).
// syncthreads drains vmcnt (stores in L2) -> fence publishes (wbl2) -> signal ->
// spin agent-scope -> fence invalidates stale L1/L2 -> syncthreads releases block.
__device__ __forceinline__ void gbar(uint_t* cnt, int epoch, int tid) {
  __syncthreads();
  if (tid == 0) {
    __threadfence();
    atomicAdd(cnt, 1u);
    uint_t tgt = (uint_t)(4 * epoch);
    while (__hip_atomic_load(cnt, __ATOMIC_RELAXED, __HIP_MEMORY_SCOPE_AGENT) < tgt)
      __builtin_amdgcn_s_sleep(4);
    __threadfence();
  }
  __syncthreads();
}

// redundant addressing over ALL 1024 fp32 mem rows; row = tid; row norm inline.
// result w -> s_scr[tid] (and s_ws[slot]). 3 internal block syncs.
__device__ __forceinline__ void addr2(
    const float* __restrict__ oarr, int slot, const float* __restrict__ rowp,
    float* __restrict__ s_ws, float* __restrict__ s_scr, float* __restrict__ s_red,
    int tid, int lane, int wave) {
  const float4* row = (const float4*)rowp;
  const float4* o4 = (const float4*)oarr;
  float dotv = 0.f, kk = 0.f, nacc = 0.f;
  #pragma unroll 4
  for (int p = 0; p < 16; ++p) {
    float4 m = row[p]; float4 o = o4[p];
    float k0 = o.x + 1e-16f, k1 = o.y + 1e-16f, k2 = o.z + 1e-16f, k3 = o.w + 1e-16f;
    float m0 = m.x + 1e-16f, m1 = m.y + 1e-16f, m2 = m.z + 1e-16f, m3 = m.w + 1e-16f;
    dotv += m0 * k0 + m1 * k1 + m2 * k2 + m3 * k3;
    kk += k0 * k0 + k1 * k1 + k2 * k2 + k3 * k3;
    nacc += m0 * m0 + m1 * m1 + m2 * m2 + m3 * m3;
  }
  float nb = fmaxf(sqrtf(kk), 1e-8f);
  float na = fmaxf(sqrtf(nacc), 1e-8f);
  float beta = splus(oarr[64]);
  float g = sigf(oarr[65]);
  float a0 = oarr[66], a1 = oarr[67], a2 = oarr[68];
  float mx = fmaxf(a0, fmaxf(a1, a2));
  float e0 = __expf(a0 - mx), e1 = __expf(a1 - mx), e2 = __expf(a2 - mx);
  float sinv = 1.0f / (e0 + e1 + e2);
  float s0 = e0 * sinv, s1 = e1 * sinv, s2 = e2 * sinv;
  float gamma = 1.0f + splus(oarr[69]);
  float z = beta * dotv / (na * nb);
  float ee = __expf(z);                    // no max-sub: |z| <= beta (small)
  float v = ee;
  #pragma unroll
  for (int o = 32; o; o >>= 1) v += __shfl_xor(v, o);
  if (lane == 0) s_red[wave] = v;
  __syncthreads();                         // (A)
  float S = 0.f;
  #pragma unroll
  for (int w = 0; w < 16; ++w) S += s_red[w];
  float wc = ee / S;
  float wgv = g * wc + (1.0f - g) * s_ws[slot * NN + tid];
  s_scr[1024 + tid] = wgv;
  __syncthreads();                         // (B)
  const float* wg = s_scr + 1024;
  float wsn = s0 * wg[(tid + 1023) & 1023] + s1 * wg[tid] + s2 * wg[(tid + 1) & 1023];
  float wp = __expf(gamma * __logf(wsn));
  v = wp;
  #pragma unroll
  for (int o = 32; o; o >>= 1) v += __shfl_xor(v, o);
  if (lane == 0) s_red[wave] = v;
  __syncthreads();                         // (C)
  float Z = 0.f;
  #pragma unroll
  for (int w = 0; w < 16; ++w) Z += s_red[w];
  float wfin = wp / (Z + 1e-16f);
  s_scr[tid] = wfin;
  s_ws[slot * NN + tid] = wfin;
}

__global__ __launch_bounds__(NTHREADS, 1) void ntm_fwd(
    const float* __restrict__ x, const float* __restrict__ mem_bias,
    const float* __restrict__ h_bias, const float* __restrict__ c_bias,
    const float* __restrict__ gbias,
    const ushort_t* __restrict__ bWih, const ushort_t* __restrict__ bWhh,
    const ushort_t* __restrict__ brW, const ushort_t* __restrict__ bwW,
    const float* __restrict__ read_b, const float* __restrict__ write_b,
    const float* __restrict__ read_init,
    const ushort_t* __restrict__ bOutW, const float* __restrict__ out_b,
    float* __restrict__ out,
    float* __restrict__ g_mem, float* __restrict__ g_h,
    float* __restrict__ g_or, float* __restrict__ g_ow,
    float* __restrict__ g_readp, uint_t* __restrict__ g_cnt) {
  const int blk = blockIdx.x;
  const int b = blk & 63;        // batch (consecutive ids -> spread over XCDs)
  const int s = blk >> 6;        // slice 0..3 (members b, b+64,.. -> same XCD on %8 map)
  const int tid = threadIdx.x;
  const int lane = tid & 63;
  const int wave = tid >> 6;
  uint_t* cntp = g_cnt + b * 32; // own 128B line per group
  int epoch = 0;

  __shared__ float s_ws[8 * NN];                 // full shift-weight history (32 KB)
  __shared__ alignas(16) float s_scr[2048];      // gates | w[0:1024] | wg/einsum[1024:]
  __shared__ alignas(16) float s_h[HH];
  __shared__ float s_c[128];                     // own c slice
  __shared__ alignas(16) float s_fx[768];        // cx (320) | final_x (768)
  __shared__ alignas(16) float s_reads[RR * VV];
  __shared__ alignas(16) float s_or[72];
  __shared__ alignas(16) float s_ow[200];
  __shared__ alignas(16) float s_e[VV];
  __shared__ alignas(16) float s_a[VV];
  __shared__ float s_red[16];

  float* memb = g_mem + (size_t)b * (NN * VV);

  { // init: full h/reads/ws redundant; own c slice; own mem slice -> global
    for (int i = tid; i < HH; i += NTHREADS) s_h[i] = h_bias[i];
    if (tid < 128) s_c[tid] = c_bias[s * 128 + tid];
    if (tid < RR * VV) s_reads[tid] = read_init[tid];
    for (int i = tid; i < 8 * NN; i += NTHREADS) s_ws[i] = 0.0f;
    int row = s * 256 + (tid >> 2), part = tid & 3;
    const float4* src = (const float4*)(mem_bias + (size_t)row * VV) + part * 4;
    float4* dst = (float4*)(memb + (size_t)row * VV) + part * 4;
    dst[0] = src[0]; dst[1] = src[1]; dst[2] = src[2]; dst[3] = src[3];
  }
  // mem-slice publish is covered by the first gbar (B1 of t=0)

  for (int t = 0; t < TT; ++t) {
    // phase0: contr_x = [x_t, reads] (s_h still holds h_{t-1})
    if (tid < DD) s_fx[tid] = x[((size_t)b * TT + t) * DD + tid];
    else if (tid < DINN) s_fx[tid] = s_reads[tid - DD];
    __syncthreads();

    // phase1: gate GEMV slice — 512 outputs/block, 2-way split-K
    {
      int o = tid >> 1, kh = tid & 1;
      int q = o >> 7, hl = o & 127;
      int j = q * 512 + s * 128 + hl;
      const uint4* wi = (const uint4*)(bWih + (size_t)j * DINN);
      const uint4* wh = (const uint4*)(bWhh + (size_t)j * HH);
      const float4* cx = (const float4*)s_fx;
      const float4* h4 = (const float4*)s_h;
      float acc = (kh == 0) ? gbias[j] : 0.f;
      #pragma unroll 4
      for (int p = 0; p < 20; ++p) {
        int u = kh * 20 + p;
        acc += dot8bf(wi[u], cx[u * 2], cx[u * 2 + 1]);
      }
      #pragma unroll 4
      for (int p = 0; p < 32; ++p) {
        int u = kh * 32 + p;
        acc += dot8bf(wh[u], h4[u * 2], h4[u * 2 + 1]);
      }
      acc += __shfl_xor(acc, 1);
      if (kh == 0) s_scr[o] = acc;
    }
    __syncthreads();
    // phase2: LSTM elementwise on own 128 h-indices; publish h_new
    if (tid < 128) {
      float gi = s_scr[tid], gf = s_scr[128 + tid];
      float gg = s_scr[256 + tid], go = s_scr[384 + tid];
      float cn = sigf(gf) * s_c[tid] + sigf(gi) * tanhf(gg);
      float hn = sigf(go) * tanhf(cn);
      s_c[tid] = cn;
      g_h[b * HH + s * 128 + tid] = hn;
    }
    gbar(cntp, ++epoch, tid);                     // B1: h ready (+ mem init at t=0)
    if (tid < HH) s_h[tid] = g_h[b * HH + tid];
    __syncthreads();

    for (int hd = 0; hd < RR; ++hd) {
      // head GEMV row-slices (read head: 18/16 rows x 8 sub; write: 50/48 x 4 sub)
      int nr = (s < 3) ? 18 : 16;
      if (tid < nr * 8) {
        int jj = s * 18 + (tid >> 3), sub = tid & 7;
        const uint4* wr = (const uint4*)(brW + (((size_t)hd * 70 + jj) << 9));
        const float4* h4 = (const float4*)s_h;
        float acc = 0.f;
        #pragma unroll
        for (int p = 0; p < 8; ++p) {
          int o = p * 16 + sub * 2;
          acc += dot8bf(wr[p * 8 + sub], h4[o], h4[o + 1]);
        }
        acc += __shfl_xor(acc, 1); acc += __shfl_xor(acc, 2); acc += __shfl_xor(acc, 4);
        if (sub == 0)
          g_or[((b * 4 + hd) * 4 + s) * 32 + (jj - s * 18)] = acc + read_b[hd * 70 + jj];
      }
      int nw = (s < 3) ? 50 : 48;
      int t2 = tid - 256;
      if (t2 >= 0 && t2 < nw * 4) {
        int jj = s * 50 + (t2 >> 2), sub = t2 & 3;
        const uint4* ww = (const uint4*)(bwW + (((size_t)hd * 198 + jj) << 9));
        const float4* h4 = (const float4*)s_h;
        float acc = 0.f;
        #pragma unroll
        for (int c = 0; c < 2; ++c) {
          #pragma unroll
          for (int p = 0; p < 8; ++p) {
            int o = (c * 8 + p) * 8 + sub * 2;
            acc += dot8bf(ww[(c * 8 + p) * 4 + sub], h4[o], h4[o + 1]);
          }
        }
        acc += __shfl_xor(acc, 1); acc += __shfl_xor(acc, 2);
        if (sub == 0)
          g_ow[((b * 4 + hd) * 4 + s) * 64 + (jj - s * 50)] = acc + write_b[hd * 198 + jj];
      }
      gbar(cntp, ++epoch, tid);                   // B2: o_r / o_w ready

      // gather full o_r / o_w from padded staging
      if (tid < 70) {
        int ss = tid / 18; if (ss > 3) ss = 3;
        s_or[tid] = g_or[((b * 4 + hd) * 4 + ss) * 32 + (tid - ss * 18)];
      } else if (tid >= 128 && tid < 326) {
        int j = tid - 128;
        int ss = j / 50; if (ss > 3) ss = 3;
        s_ow[j] = g_ow[((b * 4 + hd) * 4 + ss) * 64 + (j - ss * 50)];
      }
      __syncthreads();
      if (tid < VV) { s_e[tid] = sigf(s_ow[70 + tid]); s_a[tid] = s_ow[134 + tid]; }

      // read addressing (redundant, all rows)
      addr2(s_or, 2 * hd, memb + (size_t)tid * VV, s_ws, s_scr, s_red, tid, lane, wave);
      __syncthreads();
      // einsum partial over OWN 256 rows (wave: 16 rows, lane = column)
      {
        int row0 = s * 256 + wave * 16;
        float acc = 0.f;
        #pragma unroll
        for (int r = 0; r < 16; ++r)
          acc += s_scr[row0 + r] * memb[(size_t)(row0 + r) * VV + lane];
        s_scr[1024 + wave * 64 + lane] = acc;
      }
      __syncthreads();
      if (tid < VV) {
        float sum = 0.f;
        #pragma unroll
        for (int w = 0; w < 16; ++w) sum += s_scr[1024 + w * 64 + tid];
        g_readp[((b * 4 + hd) * 4 + s) * 64 + tid] = sum;   // published at B3a/B3b
      }
      // write addressing (redundant; its sync A orders the einsum-sum reads above)
      addr2(s_ow, 2 * hd + 1, memb + (size_t)tid * VV, s_ws, s_scr, s_red, tid, lane, wave);
      gbar(cntp, ++epoch, tid);                   // B3a: all mem READS of this head done

      // erase/add own 256 rows (4 threads/row)
      {
        int row = s * 256 + (tid >> 2), part = tid & 3;
        float w2 = s_scr[row];
        float4* rp = (float4*)(memb + (size_t)row * VV) + part * 4;
        const float4* e4 = (const float4*)s_e + part * 4;
        const float4* a4 = (const float4*)s_a + part * 4;
        #pragma unroll
        for (int q = 0; q < 4; ++q) {
          float4 m = rp[q], ev = e4[q], av = a4[q];
          m.x = m.x * (1.0f - w2 * ev.x) + w2 * av.x;
          m.y = m.y * (1.0f - w2 * ev.y) + w2 * av.y;
          m.z = m.z * (1.0f - w2 * ev.z) + w2 * av.z;
          m.w = m.w * (1.0f - w2 * ev.w) + w2 * av.w;
          rp[q] = m;
        }
      }
      gbar(cntp, ++epoch, tid);                   // B3b: new mem published
    } // heads

    // combine einsum partials -> full reads
    if (tid < RR * VV) {
      int hd = tid >> 6, v = tid & 63;
      float sum = 0.f;
      #pragma unroll
      for (int ss = 0; ss < 4; ++ss) sum += g_readp[((b * 4 + hd) * 4 + ss) * 64 + v];
      s_reads[tid] = sum;
    }
    __syncthreads();
    if (tid < 768) s_fx[tid] = (tid < HH) ? s_h[tid] : s_reads[tid - HH];
    __syncthreads();
    // out GEMV slice: 16 rows x 8 sublanes
    if (tid < 128) {
      int j = s * 16 + (tid >> 3), sub = tid & 7;
      const uint4* wo = (const uint4*)(bOutW + (size_t)j * 768);
      const float4* f4 = (const float4*)s_fx;
      float acc = 0.f;
      #pragma unroll
      for (int p = 0; p < 12; ++p) {
        int o = (p * 8 + sub) * 2;
        acc += dot8bf(wo[p * 8 + sub], f4[o], f4[o + 1]);
      }
      acc += __shfl_xor(acc, 1); acc += __shfl_xor(acc, 2); acc += __shfl_xor(acc, 4);
      if (sub == 0) out[((size_t)b * TT + t) * DD + j] = sigf(acc + out_b[j]);
    }
    __syncthreads();
  } // t
}

// ---- pre-kernels (run every launch; deterministic) ----
__global__ void f2bf_kernel(const float4* __restrict__ src, ushort4* __restrict__ dst, int n4) {
  int i = blockIdx.x * 256 + threadIdx.x;
  if (i < n4) {
    float4 v = src[i];
    ushort4 o;
    o.x = bfr(v.x); o.y = bfr(v.y); o.z = bfr(v.z); o.w = bfr(v.w);
    dst[i] = o;
  }
}
__global__ void bias_kernel(const float* __restrict__ bi, const float* __restrict__ bh,
                            float* __restrict__ o) {
  int i = blockIdx.x * 256 + threadIdx.x;
  if (i < 2048) o[i] = bi[i] + bh[i];
}
__global__ void zero_cnt(uint_t* __restrict__ p) {
  int i = blockIdx.x * 256 + threadIdx.x;
  if (i < 64 * 32) p[i] = 0u;
}

extern "C" void kernel_launch(void* const* d_in, const int* in_sizes, int n_in,
                              void* d_out, int out_size, void* d_ws, size_t ws_size,
                              hipStream_t stream) {
  char* ws = (char*)d_ws;
  float* g_mem   = (float*)ws;                      // 16,777,216
  ushort_t* bWih = (ushort_t*)(ws + 16777216);      // 1,310,720
  ushort_t* bWhh = (ushort_t*)(ws + 18087936);      // 2,097,152
  ushort_t* brW  = (ushort_t*)(ws + 20185088);      //   286,720
  ushort_t* bwW  = (ushort_t*)(ws + 20471808);      //   811,008
  ushort_t* bOutW= (ushort_t*)(ws + 21282816);      //    98,304
  float* gbias   = (float*)(ws + 21381120);         //     8,192
  float* g_h     = (float*)(ws + 21389312);         //   131,072
  float* g_or    = (float*)(ws + 21520384);         //   131,072
  float* g_ow    = (float*)(ws + 21651456);         //   262,144
  float* g_readp = (float*)(ws + 21913600);         //   262,144
  uint_t* g_cnt  = (uint_t*)(ws + 22175744);        //     8,192  (total ~22.2 MB)

  const int nWih = 2048 * DINN, nWhh = 2048 * HH, nrW = RR * 70 * HH,
            nwW = RR * 198 * HH, nOut = DD * 768;
  zero_cnt<<<8, 256, 0, stream>>>(g_cnt);
  f2bf_kernel<<<(nWih / 4 + 255) / 256, 256, 0, stream>>>((const float4*)d_in[4], (ushort4*)bWih, nWih / 4);
  f2bf_kernel<<<(nWhh / 4 + 255) / 256, 256, 0, stream>>>((const float4*)d_in[5], (ushort4*)bWhh, nWhh / 4);
  f2bf_kernel<<<(nrW / 4 + 255) / 256, 256, 0, stream>>>((const float4*)d_in[8], (ushort4*)brW, nrW / 4);
  f2bf_kernel<<<(nwW / 4 + 255) / 256, 256, 0, stream>>>((const float4*)d_in[10], (ushort4*)bwW, nwW / 4);
  f2bf_kernel<<<(nOut / 4 + 255) / 256, 256, 0, stream>>>((const float4*)d_in[13], (ushort4*)bOutW, nOut / 4);
  bias_kernel<<<8, 256, 0, stream>>>((const float*)d_in[6], (const float*)d_in[7], gbias);

  ntm_fwd<<<dim3(256), dim3(NTHREADS), 0, stream>>>(
      (const float*)d_in[0], (const float*)d_in[1], (const float*)d_in[2],
      (const float*)d_in[3], gbias, bWih, bWhh, brW, bwW,
      (const float*)d_in[9], (const float*)d_in[11], (const float*)d_in[12],
      bOutW, (const float*)d_in[14],
      (float*)d_out, g_mem, g_h, g_or, g_ow, g_readp, g_cnt);
}